// Round 1
// 785.715 us; speedup vs baseline: 1.0656x; 1.0656x over previous
//
#include <hip/hip_runtime.h>

#define MID 3
#define NVEC 32
#define ROW_F 96   // MID*NVEC

#define CHUNK 8      // edges per side per staging sub-chunk
#define CH_F  128    // floats staged per edge: 96 xe + 32 W

// ---------------------------------------------------------------------------
// Device-built CSR over 2N segments: seg n   = edges with dst==n  (side 1)
//                                    seg N+n = edges with src==n  (side 2)
// ws layout (ints): counts[2N] | offsets[2N] | rank1[E] | rank2[E] | list[2E] | bsum[256]
// hist records each edge's within-segment rank from the atomicAdd return, so
// scatter needs NO atomics (was 2 returning atomics/edge).
// ---------------------------------------------------------------------------

__global__ __launch_bounds__(256) void hist_kernel(
    const int* __restrict__ dst, const int* __restrict__ src,
    int* __restrict__ cnt, int* __restrict__ rank1, int* __restrict__ rank2,
    int E, int N)
{
    int t = blockIdx.x * blockDim.x + threadIdx.x;
    if (t >= E) return;
    rank1[t] = atomicAdd(&cnt[dst[t]], 1);
    rank2[t] = atomicAdd(&cnt[N + src[t]], 1);
}

// --- parallel scan: A) per-block sums, B) scan of block sums, C) local scan+add
#define SCAN_TPB 256
#define SCAN_EPB 1024   // elems per block (4 per thread, int4)

__global__ __launch_bounds__(SCAN_TPB) void scanA_kernel(
    const int* __restrict__ cnt, int* __restrict__ bsum, int n)
{
    __shared__ int sdata[SCAN_TPB];
    int b = blockIdx.x, t = threadIdx.x;
    int i4 = b * SCAN_EPB + t * 4;
    int s = 0;
    if (i4 + 3 < n) {
        int4 v = *(const int4*)(cnt + i4);
        s = v.x + v.y + v.z + v.w;
    } else {
        for (int k = 0; k < 4; ++k) if (i4 + k < n) s += cnt[i4 + k];
    }
    sdata[t] = s;
    __syncthreads();
    for (int o = SCAN_TPB / 2; o > 0; o >>= 1) {
        if (t < o) sdata[t] += sdata[t + o];
        __syncthreads();
    }
    if (t == 0) bsum[b] = sdata[0];
}

__global__ __launch_bounds__(SCAN_TPB) void scanB_kernel(
    int* __restrict__ bsum, int nb)   // in-place exclusive scan, nb <= 256
{
    __shared__ int sdata[SCAN_TPB];
    int t = threadIdx.x;
    int v = (t < nb) ? bsum[t] : 0;
    sdata[t] = v;
    __syncthreads();
    for (int o = 1; o < SCAN_TPB; o <<= 1) {
        int u = (t >= o) ? sdata[t - o] : 0;
        __syncthreads();
        sdata[t] += u;
        __syncthreads();
    }
    if (t < nb) bsum[t] = sdata[t] - v;   // exclusive
}

__global__ __launch_bounds__(SCAN_TPB) void scanC_kernel(
    const int* __restrict__ cnt, const int* __restrict__ bsum,
    int* __restrict__ off, int n)
{
    __shared__ int sdata[SCAN_TPB];
    int b = blockIdx.x, t = threadIdx.x;
    int i4 = b * SCAN_EPB + t * 4;
    int4 v = make_int4(0, 0, 0, 0);
    if (i4 + 3 < n) {
        v = *(const int4*)(cnt + i4);
    } else {
        if (i4 + 0 < n) v.x = cnt[i4 + 0];
        if (i4 + 1 < n) v.y = cnt[i4 + 1];
        if (i4 + 2 < n) v.z = cnt[i4 + 2];
    }
    int tot = v.x + v.y + v.z + v.w;
    sdata[t] = tot;
    __syncthreads();
    for (int o = 1; o < SCAN_TPB; o <<= 1) {
        int u = (t >= o) ? sdata[t - o] : 0;
        __syncthreads();
        sdata[t] += u;
        __syncthreads();
    }
    int run = bsum[b] + sdata[t] - tot;    // exclusive prefix of this thread's 4
    int4 o4;
    o4.x = run;
    o4.y = run + v.x;
    o4.z = run + v.x + v.y;
    o4.w = run + v.x + v.y + v.z;
    if (i4 + 3 < n) {
        *(int4*)(off + i4) = o4;
    } else {
        if (i4 + 0 < n) off[i4 + 0] = o4.x;
        if (i4 + 1 < n) off[i4 + 1] = o4.y;
        if (i4 + 2 < n) off[i4 + 2] = o4.z;
    }
}

__global__ __launch_bounds__(256) void scatter_kernel(
    const int* __restrict__ dst, const int* __restrict__ src,
    const int* __restrict__ off,
    const int* __restrict__ rank1, const int* __restrict__ rank2,
    int* __restrict__ list, int E, int N)
{
    int t = blockIdx.x * blockDim.x + threadIdx.x;
    if (t >= E) return;
    list[off[dst[t]] + rank1[t]] = t;        // no atomics
    list[off[N + src[t]] + rank2[t]] = t;
}

// ---------------------------------------------------------------------------
// One 64-lane wave per node. Lanes 0-31: dst-edge sum (x1). Lanes 32-63:
// src-edge sum (x2). Edge data (96f xe + 32f W per edge) is DMA'd into a
// per-wave-private LDS buffer with global_load_lds (per-lane global source,
// wave-uniform LDS base + lane*4). 8 edges/side in flight per sub-chunk at
// zero VGPR cost; per-wave vmcnt(0) wait, NO block barrier in the loop.
// Consume is stride-1 ds_read (conflict-free). Then fused mix via shfl.
// ---------------------------------------------------------------------------

__device__ __forceinline__ void stage_edge(
    const float* __restrict__ xe, const float* __restrict__ W,
    int e, int lane, float* ldsbase /* 128-float slot, wave-uniform */)
{
    // instr 1: floats [0..63]  <- xe[e][0..1][.]   (lane i -> xe row float i)
    // instr 2: floats [64..95] <- xe[e][2][.]      (lanes 0..31)
    //          floats [96..127]<- W[e][.]          (lanes 32..63)
    const float* g1 = xe + (size_t)e * ROW_F + lane;
    const float* g2 = (lane < 32) ? (xe + (size_t)e * ROW_F + 64 + lane)
                                  : (W  + (size_t)e * NVEC + (lane - 32));
    __builtin_amdgcn_global_load_lds(
        (const __attribute__((address_space(1))) void*)g1,
        (__attribute__((address_space(3))) void*)ldsbase, 4, 0, 0);
    __builtin_amdgcn_global_load_lds(
        (const __attribute__((address_space(1))) void*)g2,
        (__attribute__((address_space(3))) void*)(ldsbase + 64), 4, 0, 0);
}

__global__ __launch_bounds__(256) void gather_mix_kernel(
    const float* __restrict__ xe,     // [E,3,32]
    const float* __restrict__ W,      // [E,32]
    const float* __restrict__ M1, const float* __restrict__ M2,
    const int* __restrict__ cnt, const int* __restrict__ off,
    const int* __restrict__ list,
    float* __restrict__ out,          // [N,3,32]
    int N, int E2)                    // E2 = 2*E (list length)
{
    __shared__ float As[NVEC * NVEC];
    __shared__ float Bs[NVEC * NVEC];
    __shared__ float sbuf[4][2][CHUNK * CH_F];   // 4 waves x 2 sides x 4KB = 32KB

    for (int i = threadIdx.x; i < NVEC * NVEC; i += blockDim.x) {
        float m1 = M1[i], m2 = M2[i];
        As[i] = 0.5f * (m1 + m2);
        Bs[i] = 0.5f * (m2 - m1);
    }
    __syncthreads();

    int wave = threadIdx.x >> 6;                 // 0..3
    int n = blockIdx.x * 4 + wave;
    if (n >= N) return;
    int lane = threadIdx.x & 63;
    int half = lane >> 5;                         // 0 = dst side, 1 = src side
    int l = lane & 31;

    int cD = cnt[n],  cS = cnt[N + n];
    int baseD = off[n], baseS = off[N + n];

    float* bufD = &sbuf[wave][0][0];
    float* bufS = &sbuf[wave][1][0];
    float* mybuf  = half ? bufS  : bufD;
    int    myC    = half ? cS    : cD;
    int    myBase = half ? baseS : baseD;

    float acc0 = 0.f, acc1 = 0.f, acc2 = 0.f;
    int cMax = cD > cS ? cD : cS;

    for (int i0 = 0; i0 < cMax; i0 += 32) {
        // cooperative edge-id chunk load: lanes 0-31 dst ids, 32-63 src ids
        int idx = i0 + l;
        int cl = idx < myC ? idx : (myC - 1);
        if (cl < 0) cl = 0;
        int li = myBase + cl;
        if (li >= E2) li = E2 - 1;
        int eidv = list[li];

        for (int s = 0; s < 4; ++s) {
            int sD = cD - i0 - s * CHUNK; sD = sD < 0 ? 0 : (sD > CHUNK ? CHUNK : sD);
            int sS = cS - i0 - s * CHUNK; sS = sS < 0 ? 0 : (sS > CHUNK ? CHUNK : sS);
            if ((sD | sS) == 0) break;

            // previous sub-chunk's ds_reads must land before DMA overwrites
            asm volatile("s_waitcnt lgkmcnt(0)" ::: "memory");

            for (int j = 0; j < sD; ++j) {        // uniform trip (sD uniform)
                int e = __shfl(eidv, s * CHUNK + j, 64);
                stage_edge(xe, W, e, lane, bufD + j * CH_F);
            }
            for (int j = 0; j < sS; ++j) {
                int e = __shfl(eidv, 32 + s * CHUNK + j, 64);
                stage_edge(xe, W, e, lane, bufS + j * CH_F);
            }
            asm volatile("s_waitcnt vmcnt(0)" ::: "memory");

            int lim = half ? sS : sD;
            for (int j = 0; j < lim; ++j) {
                const float* p = mybuf + j * CH_F;
                float w = p[96 + l];
                acc0 += w * p[l];
                acc1 += w * p[32 + l];
                acc2 += w * p[64 + l];
            }
        }
    }

    // mix: out[m][l] = sum_v x1[m][v]*A[v][l] + x2[m][v]*B[v][l]
    float o0 = 0.f, o1 = 0.f, o2 = 0.f;
    #pragma unroll
    for (int v = 0; v < NVEC; ++v) {
        float a = As[v * NVEC + l];
        float b = Bs[v * NVEC + l];
        o0 += __shfl(acc0, v, 64) * a + __shfl(acc0, 32 + v, 64) * b;
        o1 += __shfl(acc1, v, 64) * a + __shfl(acc1, 32 + v, 64) * b;
        o2 += __shfl(acc2, v, 64) * a + __shfl(acc2, 32 + v, 64) * b;
    }
    if (half == 0) {
        float* orow = out + (size_t)n * ROW_F;
        orow[l]      = o0;
        orow[32 + l] = o1;
        orow[64 + l] = o2;
    }
}

extern "C" void kernel_launch(void* const* d_in, const int* in_sizes, int n_in,
                              void* d_out, int out_size, void* d_ws, size_t ws_size,
                              hipStream_t stream)
{
    const float* xe  = (const float*)d_in[0];
    const float* W   = (const float*)d_in[1];
    const float* M1  = (const float*)d_in[2];
    const float* M2  = (const float*)d_in[3];
    const int* xsrc  = (const int*)d_in[4];
    const int* xdst  = (const int*)d_in[5];

    const int E = in_sizes[4];
    const int N = out_size / ROW_F;
    const int nseg = 2 * N;

    int* wsi     = (int*)d_ws;
    int* counts  = wsi;                       // 2N
    int* offsets = wsi + nseg;                // 2N
    int* rank1   = wsi + 2 * nseg;            // E
    int* rank2   = wsi + 2 * nseg + E;        // E
    int* list    = wsi + 2 * nseg + 2 * E;    // 2E
    int* bsum    = wsi + 2 * nseg + 4 * E;    // 256
    // ws need: (4N + 4E + 256)*4 ~= 13.6 MB

    hipMemsetAsync(counts, 0, (size_t)nseg * sizeof(int), stream);

    const int eblocks = (E + 255) / 256;
    hist_kernel<<<eblocks, 256, 0, stream>>>(xdst, xsrc, counts, rank1, rank2, E, N);

    const int nscan = (nseg + SCAN_EPB - 1) / SCAN_EPB;   // <= 256 blocks
    scanA_kernel<<<nscan, SCAN_TPB, 0, stream>>>(counts, bsum, nseg);
    scanB_kernel<<<1, SCAN_TPB, 0, stream>>>(bsum, nscan);
    scanC_kernel<<<nscan, SCAN_TPB, 0, stream>>>(counts, bsum, offsets, nseg);

    scatter_kernel<<<eblocks, 256, 0, stream>>>(xdst, xsrc, offsets, rank1, rank2, list, E, N);

    const int nblocks = (N + 3) / 4;              // 4 nodes (waves) per block
    gather_mix_kernel<<<nblocks, 256, 0, stream>>>(
        xe, W, M1, M2, counts, offsets, list, (float*)d_out, N, 2 * E);
}

// Round 2
// 628.844 us; speedup vs baseline: 1.3315x; 1.2495x over previous
//
#include <hip/hip_runtime.h>

#define MID 3
#define NVEC 32
#define ROW_F 96   // MID*NVEC

// ---------------------------------------------------------------------------
// Device-built CSR over 2N segments: seg n   = edges with dst==n  (side 1)
//                                    seg N+n = edges with src==n  (side 2)
// ws layout (ints): counts[2N] | offsets[2N] | rank1[E] | rank2[E] | list[2E] | bsum[256]
// hist records each edge's within-segment rank from the atomicAdd return, so
// scatter needs NO atomics.
// ---------------------------------------------------------------------------

__global__ __launch_bounds__(256) void hist_kernel(
    const int* __restrict__ dst, const int* __restrict__ src,
    int* __restrict__ cnt, int* __restrict__ rank1, int* __restrict__ rank2,
    int E, int N)
{
    int t = blockIdx.x * blockDim.x + threadIdx.x;
    if (t >= E) return;
    rank1[t] = atomicAdd(&cnt[dst[t]], 1);
    rank2[t] = atomicAdd(&cnt[N + src[t]], 1);
}

// --- parallel scan: A) per-block sums, B) scan of block sums, C) local scan+add
#define SCAN_TPB 256
#define SCAN_EPB 1024   // elems per block (4 per thread, int4)

__global__ __launch_bounds__(SCAN_TPB) void scanA_kernel(
    const int* __restrict__ cnt, int* __restrict__ bsum, int n)
{
    __shared__ int sdata[SCAN_TPB];
    int b = blockIdx.x, t = threadIdx.x;
    int i4 = b * SCAN_EPB + t * 4;
    int s = 0;
    if (i4 + 3 < n) {
        int4 v = *(const int4*)(cnt + i4);
        s = v.x + v.y + v.z + v.w;
    } else {
        for (int k = 0; k < 4; ++k) if (i4 + k < n) s += cnt[i4 + k];
    }
    sdata[t] = s;
    __syncthreads();
    for (int o = SCAN_TPB / 2; o > 0; o >>= 1) {
        if (t < o) sdata[t] += sdata[t + o];
        __syncthreads();
    }
    if (t == 0) bsum[b] = sdata[0];
}

__global__ __launch_bounds__(SCAN_TPB) void scanB_kernel(
    int* __restrict__ bsum, int nb)   // in-place exclusive scan, nb <= 256
{
    __shared__ int sdata[SCAN_TPB];
    int t = threadIdx.x;
    int v = (t < nb) ? bsum[t] : 0;
    sdata[t] = v;
    __syncthreads();
    for (int o = 1; o < SCAN_TPB; o <<= 1) {
        int u = (t >= o) ? sdata[t - o] : 0;
        __syncthreads();
        sdata[t] += u;
        __syncthreads();
    }
    if (t < nb) bsum[t] = sdata[t] - v;   // exclusive
}

__global__ __launch_bounds__(SCAN_TPB) void scanC_kernel(
    const int* __restrict__ cnt, const int* __restrict__ bsum,
    int* __restrict__ off, int n)
{
    __shared__ int sdata[SCAN_TPB];
    int b = blockIdx.x, t = threadIdx.x;
    int i4 = b * SCAN_EPB + t * 4;
    int4 v = make_int4(0, 0, 0, 0);
    if (i4 + 3 < n) {
        v = *(const int4*)(cnt + i4);
    } else {
        if (i4 + 0 < n) v.x = cnt[i4 + 0];
        if (i4 + 1 < n) v.y = cnt[i4 + 1];
        if (i4 + 2 < n) v.z = cnt[i4 + 2];
    }
    int tot = v.x + v.y + v.z + v.w;
    sdata[t] = tot;
    __syncthreads();
    for (int o = 1; o < SCAN_TPB; o <<= 1) {
        int u = (t >= o) ? sdata[t - o] : 0;
        __syncthreads();
        sdata[t] += u;
        __syncthreads();
    }
    int run = bsum[b] + sdata[t] - tot;    // exclusive prefix of this thread's 4
    int4 o4;
    o4.x = run;
    o4.y = run + v.x;
    o4.z = run + v.x + v.y;
    o4.w = run + v.x + v.y + v.z;
    if (i4 + 3 < n) {
        *(int4*)(off + i4) = o4;
    } else {
        if (i4 + 0 < n) off[i4 + 0] = o4.x;
        if (i4 + 1 < n) off[i4 + 1] = o4.y;
        if (i4 + 2 < n) off[i4 + 2] = o4.z;
    }
}

__global__ __launch_bounds__(256) void scatter_kernel(
    const int* __restrict__ dst, const int* __restrict__ src,
    const int* __restrict__ off,
    const int* __restrict__ rank1, const int* __restrict__ rank2,
    int* __restrict__ list, int E, int N)
{
    int t = blockIdx.x * blockDim.x + threadIdx.x;
    if (t >= E) return;
    list[off[dst[t]] + rank1[t]] = t;        // no atomics
    list[off[N + src[t]] + rank2[t]] = t;
}

// ---------------------------------------------------------------------------
// One 64-lane wave per node; sides processed SEQUENTIALLY by the full wave
// (removes cD/cS imbalance). Within a side, half h handles edges at positions
// == h (mod 2); lane (h,l) accumulates vector component l.
//
// Edge-id access: one coalesced load per 64-edge superchunk puts id[2l+h] in
// each lane; per 8-edge group, 4 independent shfls broadcast the ids (no
// per-edge memory latency). Edge data: plain register loads, 2-deep software
// pipeline (issue group g+1's 16 loads, consume group g) -- the compiler's
// exact per-value vmcnt(N) keeps g+1's loads in flight across g's consume.
// Tail: clamp id (same cache lines), zero w at consume.
//
// Mix phase: halves split the v-sum (16 terms each) + one xor-combine;
// 105 shuffles vs 192 before.
// ---------------------------------------------------------------------------

#define ISSUE(G, wv, xv)                                                    \
  { _Pragma("unroll")                                                       \
    for (int k_ = 0; k_ < 4; ++k_) {                                        \
      int e_ = __shfl(idv, (h << 5) + ((G) << 2) + k_, 64);                 \
      const float* xp_ = xe + (size_t)e_ * ROW_F + l;                       \
      wv[k_]      = W[(size_t)e_ * NVEC + l];                               \
      xv[k_*3+0]  = xp_[0];                                                 \
      xv[k_*3+1]  = xp_[32];                                                \
      xv[k_*3+2]  = xp_[64];                                                \
    } }

#define CONSUME(G, wv, xv)                                                  \
  { _Pragma("unroll")                                                       \
    for (int k_ = 0; k_ < 4; ++k_) {                                        \
      int pos_ = i0 + ((G) << 3) + 2*k_ + h;                                \
      float wk_ = (pos_ < c) ? wv[k_] : 0.f;                                \
      a0 += wk_ * xv[k_*3+0];                                               \
      a1 += wk_ * xv[k_*3+1];                                               \
      a2 += wk_ * xv[k_*3+2];                                               \
    } }

__global__ __launch_bounds__(256, 4) void gather_mix_kernel(
    const float* __restrict__ xe,     // [E,3,32]
    const float* __restrict__ W,      // [E,32]
    const float* __restrict__ M1, const float* __restrict__ M2,
    const int* __restrict__ cnt, const int* __restrict__ off,
    const int* __restrict__ list,
    float* __restrict__ out,          // [N,3,32]
    int N)
{
    __shared__ float As[NVEC * NVEC];
    __shared__ float Bs[NVEC * NVEC];
    for (int i = threadIdx.x; i < NVEC * NVEC; i += blockDim.x) {
        float m1 = M1[i], m2 = M2[i];
        As[i] = 0.5f * (m1 + m2);
        Bs[i] = 0.5f * (m2 - m1);
    }
    __syncthreads();

    int wave = threadIdx.x >> 6;                 // 0..3
    int n = blockIdx.x * 4 + wave;
    if (n >= N) return;
    int lane = threadIdx.x & 63;
    int h = lane >> 5;                            // even/odd edge half
    int l = lane & 31;                            // vector component

    float accD0 = 0.f, accD1 = 0.f, accD2 = 0.f;
    float accS0 = 0.f, accS1 = 0.f, accS2 = 0.f;

    #pragma unroll
    for (int side = 0; side < 2; ++side) {
        int seg  = side ? (N + n) : n;
        int c    = __builtin_amdgcn_readfirstlane(cnt[seg]);
        int base = __builtin_amdgcn_readfirstlane(off[seg]);

        float a0 = 0.f, a1 = 0.f, a2 = 0.f;

        for (int i0 = 0; i0 < c; i0 += 64) {
            int rem = c - i0; if (rem > 64) rem = 64;
            int p2  = 2 * l + h;
            int idv = list[base + i0 + (p2 < rem ? p2 : rem - 1)];
            int ng  = (rem + 7) >> 3;            // groups of 8 edges

            float wA[4], xA[12], wB[4], xB[12];
            ISSUE(0, wA, xA);
            int g = 0;
            while (true) {
                if (g + 1 < ng) ISSUE(g + 1, wB, xB);
                CONSUME(g, wA, xA);
                ++g; if (g >= ng) break;
                if (g + 1 < ng) ISSUE(g + 1, wA, xA);
                CONSUME(g, wB, xB);
                ++g; if (g >= ng) break;
            }
        }

        if (side == 0) { accD0 = a0; accD1 = a1; accD2 = a2; }
        else           { accS0 = a0; accS1 = a1; accS2 = a2; }
    }

    // combine even/odd-edge partials: all lanes get the full per-component sum
    accD0 += __shfl_xor(accD0, 32, 64);
    accD1 += __shfl_xor(accD1, 32, 64);
    accD2 += __shfl_xor(accD2, 32, 64);
    accS0 += __shfl_xor(accS0, 32, 64);
    accS1 += __shfl_xor(accS1, 32, 64);
    accS2 += __shfl_xor(accS2, 32, 64);

    // mix: out[m][l] = sum_v accD[m][v]*A[v][l] + accS[m][v]*B[v][l]
    // halves split the v-range (16 each), then xor-combine.
    float o0 = 0.f, o1 = 0.f, o2 = 0.f;
    int vbase = h << 4;
    #pragma unroll
    for (int j = 0; j < 16; ++j) {
        int v = vbase + j;
        float Av = As[v * NVEC + l];
        float Bv = Bs[v * NVEC + l];
        float d0 = __shfl(accD0, v, 64), s0 = __shfl(accS0, v, 64);
        float d1 = __shfl(accD1, v, 64), s1 = __shfl(accS1, v, 64);
        float d2 = __shfl(accD2, v, 64), s2 = __shfl(accS2, v, 64);
        o0 += d0 * Av + s0 * Bv;
        o1 += d1 * Av + s1 * Bv;
        o2 += d2 * Av + s2 * Bv;
    }
    o0 += __shfl_xor(o0, 32, 64);
    o1 += __shfl_xor(o1, 32, 64);
    o2 += __shfl_xor(o2, 32, 64);

    float* orow = out + (size_t)n * ROW_F;
    orow[lane] = h ? o1 : o0;        // lanes 0-31 -> row0, 32-63 -> row1
    if (!h) orow[64 + l] = o2;       // half 0 writes row2
}

extern "C" void kernel_launch(void* const* d_in, const int* in_sizes, int n_in,
                              void* d_out, int out_size, void* d_ws, size_t ws_size,
                              hipStream_t stream)
{
    const float* xe  = (const float*)d_in[0];
    const float* W   = (const float*)d_in[1];
    const float* M1  = (const float*)d_in[2];
    const float* M2  = (const float*)d_in[3];
    const int* xsrc  = (const int*)d_in[4];
    const int* xdst  = (const int*)d_in[5];

    const int E = in_sizes[4];
    const int N = out_size / ROW_F;
    const int nseg = 2 * N;

    int* wsi     = (int*)d_ws;
    int* counts  = wsi;                       // 2N
    int* offsets = wsi + nseg;                // 2N
    int* rank1   = wsi + 2 * nseg;            // E
    int* rank2   = wsi + 2 * nseg + E;        // E
    int* list    = wsi + 2 * nseg + 2 * E;    // 2E
    int* bsum    = wsi + 2 * nseg + 4 * E;    // 256
    // ws need: (4N + 4E + 256)*4 ~= 13.6 MB

    hipMemsetAsync(counts, 0, (size_t)nseg * sizeof(int), stream);

    const int eblocks = (E + 255) / 256;
    hist_kernel<<<eblocks, 256, 0, stream>>>(xdst, xsrc, counts, rank1, rank2, E, N);

    const int nscan = (nseg + SCAN_EPB - 1) / SCAN_EPB;   // <= 256 blocks
    scanA_kernel<<<nscan, SCAN_TPB, 0, stream>>>(counts, bsum, nseg);
    scanB_kernel<<<1, SCAN_TPB, 0, stream>>>(bsum, nscan);
    scanC_kernel<<<nscan, SCAN_TPB, 0, stream>>>(counts, bsum, offsets, nseg);

    scatter_kernel<<<eblocks, 256, 0, stream>>>(xdst, xsrc, offsets, rank1, rank2, list, E, N);

    const int nblocks = (N + 3) / 4;              // 4 nodes (waves) per block
    gather_mix_kernel<<<nblocks, 256, 0, stream>>>(
        xe, W, M1, M2, counts, offsets, list, (float*)d_out, N);
}